// Round 3
// baseline (320.319 us; speedup 1.0000x reference)
//
#include <hip/hip_runtime.h>
#include <cstdint>
#include <cstddef>
#include <type_traits>

typedef float  f32x4    __attribute__((ext_vector_type(4)));
typedef __bf16 bf16x8   __attribute__((ext_vector_type(8)));
typedef short  short4_t __attribute__((ext_vector_type(4)));
typedef short  short8_t __attribute__((ext_vector_type(8)));

__device__ __forceinline__ short f2bf(float f) {
  return __builtin_bit_cast(short, (__bf16)f);   // hw cvt, RNE
}

// ---------------- transpose-convert W[K][N] fp32 -> WT[N][K] bf16 ----------------
__global__ void transpose_bf16(const float* __restrict__ W, short* __restrict__ WT,
                               int K, int N) {
  __shared__ float tile[32][33];
  int tx = threadIdx.x & 31, ty = threadIdx.x >> 5;
  int n0 = blockIdx.x * 32, k0 = blockIdx.y * 32;
#pragma unroll
  for (int i = 0; i < 32; i += 8)
    tile[ty + i][tx] = W[(size_t)(k0 + ty + i) * N + n0 + tx];
  __syncthreads();
#pragma unroll
  for (int i = 0; i < 32; i += 8)
    WT[(size_t)(n0 + ty + i) * K + k0 + tx] = f2bf(tile[tx][ty + i]);
}

// ---------------- pipelined bf16 GEMM, Bt is [N][K] bf16 ----------------
// A: fp32 (AF32) or bf16. Register-prefetch staging: global->VGPR issued a full
// compute phase before the VGPR->LDS write, so the barrier drains only lgkmcnt.
// MODE 0: fp32 out [M][N].  MODE 1: Q/K [B,H,T,D] via LDS-coalesced stores,
// V^T [B,H,D,T] via packed direct stores.
template <int MODE, bool AF32>
__global__ __launch_bounds__(256, 4) void gemm_bt(
    const void* __restrict__ Av, const short* __restrict__ Bt,
    float* __restrict__ outf, short* __restrict__ Qo, short* __restrict__ Ko,
    short* __restrict__ Vo, int M, int N, int K) {
  constexpr int SMEM = (MODE == 1) ? (128 * 136 * 2) : 16384;
  __shared__ alignas(16) char smem[SMEM];
  short* As = (short*)smem;             // [128][32]
  short* Bs = (short*)(smem + 8192);    // [128][32]

  const int tid = threadIdx.x;
  const int lane = tid & 63, wave = tid >> 6;
  const int g = lane & 15, q = lane >> 4;
  const int m0 = blockIdx.y * 128, n0 = blockIdx.x * 128;
  const int wm = (wave >> 1) * 64, wn = (wave & 1) * 64;

  const int srow = tid >> 2;            // 0..63
  const int scol = (tid & 3) * 8;
  const float* Af = (const float*)Av;
  const short* Ab = (const short*)Av;

  f32x4    raf[4];
  short8_t ra[2], rb[2];

  auto load_regs = [&](int k0) {
    if constexpr (AF32) {
      const float* p0 = &Af[(size_t)(m0 + srow) * K + k0 + scol];
      const float* p1 = &Af[(size_t)(m0 + 64 + srow) * K + k0 + scol];
      raf[0] = *(const f32x4*)p0; raf[1] = *(const f32x4*)(p0 + 4);
      raf[2] = *(const f32x4*)p1; raf[3] = *(const f32x4*)(p1 + 4);
    } else {
      ra[0] = *(const short8_t*)&Ab[(size_t)(m0 + srow) * K + k0 + scol];
      ra[1] = *(const short8_t*)&Ab[(size_t)(m0 + 64 + srow) * K + k0 + scol];
    }
    rb[0] = *(const short8_t*)&Bt[(size_t)(n0 + srow) * K + k0 + scol];
    rb[1] = *(const short8_t*)&Bt[(size_t)(n0 + 64 + srow) * K + k0 + scol];
  };
  auto store_regs = [&]() {
    short8_t w0, w1;
    if constexpr (AF32) {
#pragma unroll
      for (int j = 0; j < 4; j++) {
        w0[j] = f2bf(raf[0][j]); w0[4 + j] = f2bf(raf[1][j]);
        w1[j] = f2bf(raf[2][j]); w1[4 + j] = f2bf(raf[3][j]);
      }
    } else { w0 = ra[0]; w1 = ra[1]; }
    *(short8_t*)&As[tid * 8] = w0;
    *(short8_t*)&As[(tid + 256) * 8] = w1;
    *(short8_t*)&Bs[tid * 8] = rb[0];
    *(short8_t*)&Bs[(tid + 256) * 8] = rb[1];
  };

  f32x4 acc[4][4] = {};
  const int KB = K >> 5;
  load_regs(0);
  for (int kb = 0; kb < KB; kb++) {
    __syncthreads();                 // prior tile's consumers done
    store_regs();                    // waits vmcnt (issued a phase ago)
    if (kb + 1 < KB) load_regs((kb + 1) << 5);  // fly during compute
    __syncthreads();
    bf16x8 af[4], bfr[4];
#pragma unroll
    for (int mt = 0; mt < 4; mt++)
      af[mt] = *(const bf16x8*)&As[(wm + mt * 16 + g) * 32 + q * 8];
#pragma unroll
    for (int nt = 0; nt < 4; nt++)
      bfr[nt] = *(const bf16x8*)&Bs[(wn + nt * 16 + g) * 32 + q * 8];
#pragma unroll
    for (int mt = 0; mt < 4; mt++)
#pragma unroll
      for (int nt = 0; nt < 4; nt++)
        acc[mt][nt] = __builtin_amdgcn_mfma_f32_16x16x32_bf16(af[mt], bfr[nt],
                                                              acc[mt][nt], 0, 0, 0);
  }

  if (MODE == 0) {
#pragma unroll
    for (int mt = 0; mt < 4; mt++)
#pragma unroll
      for (int nt = 0; nt < 4; nt++) {
        int n = n0 + wn + nt * 16 + g;
        int mbase = m0 + wm + mt * 16 + q * 4;
#pragma unroll
        for (int r = 0; r < 4; r++)
          outf[(size_t)(mbase + r) * N + n] = acc[mt][nt][r];
      }
  } else {
    const int which = n0 >> 10;          // uniform per block (128 | 1024)
    const int b = m0 >> 11;              // uniform per block (128 | 2048)
    if (which == 2) {
      // V^T [b,h,d,t]: t consecutive over r -> packed 8B stores
#pragma unroll
      for (int nt = 0; nt < 4; nt++) {
        int c = (n0 + wn + nt * 16 + g) & 1023;
        int h = c >> 6, d = c & 63;
#pragma unroll
        for (int mt = 0; mt < 4; mt++) {
          int t = (m0 + wm + mt * 16 + q * 4) & 2047;
          short4_t pv;
#pragma unroll
          for (int r = 0; r < 4; r++) pv[r] = f2bf(acc[mt][nt][r]);
          *(short4_t*)&Vo[((size_t)((b << 4) + h) * 64 + d) * 2048 + t] = pv;
        }
      }
    } else {
      // Q/K: stage C-tile in LDS, store coalesced 16B
      __syncthreads();
      short* Cs = (short*)smem;          // [128][136]
#pragma unroll
      for (int mt = 0; mt < 4; mt++)
#pragma unroll
        for (int nt = 0; nt < 4; nt++)
#pragma unroll
          for (int r = 0; r < 4; r++)
            Cs[(wm + mt * 16 + q * 4 + r) * 136 + wn + nt * 16 + g] =
                f2bf(acc[mt][nt][r]);
      __syncthreads();
      short* dst = (which == 0) ? Qo : Ko;
      const int h0 = (n0 & 1023) >> 6;
      const int trow = tid >> 1, half = tid & 1;
      const int t = (m0 + trow) & 2047;
      const size_t gb = ((size_t)((b << 4) + h0 + half) * 2048 + t) * 64;
#pragma unroll
      for (int j = 0; j < 8; j++)
        *(short8_t*)&dst[gb + j * 8] =
            *(const short8_t*)&Cs[trow * 136 + half * 64 + j * 8];
    }
  }
}

// ---------------- causal flash attention ----------------
// Q,K: [B,H,T,D] bf16.  Vt: [B,H,D,T] bf16.  O: [B,T,H*D] bf16.
// One q-tile (128 rows) per block; 1024 blocks, qt descending (heavy first),
// bh in low 6 bits of id so each (b,h)'s K/V pins to one XCD L2 (id%8==bh%8).
// Q frags loaded direct from global (no staging). P buffer is half-width
// (64 keys), reused across the two kk-halves (same-wave in-order DS ops).
__global__ __launch_bounds__(256, 3) void attn_fwd(
    const short* __restrict__ Qg, const short* __restrict__ Kg,
    const short* __restrict__ Vt, short* __restrict__ Og) {
  __shared__ alignas(16) short Ks[128 * 72];     // [key][64+8]
  __shared__ alignas(16) short VTs[64 * 136];    // [d][128+8]
  __shared__ alignas(16) short Ps[4][32 * 72];   // per-wave P [32 qrows][64+8]

  const int tid = threadIdx.x, lane = tid & 63, wave = tid >> 6;
  const int g = lane & 15, q = lane >> 4;
  const int id = blockIdx.x;
  const int bh = id & 63;
  const int qt = 15 - (id >> 6);
  const size_t base = (size_t)bh * (2048 * 64);
  const int b = bh >> 4, h = bh & 15;
  const float cs = 0.18033688011f;     // (1/sqrt(64)) * log2(e)

  // Q fragments: direct global loads, pre-scaled
  bf16x8 bq[2][2];
  {
    const short* Qp = Qg + base + (size_t)qt * 128 * 64;
#pragma unroll
    for (int nt = 0; nt < 2; nt++)
#pragma unroll
      for (int kk = 0; kk < 2; kk++) {
        bf16x8 v = *(const bf16x8*)&Qp[(wave * 32 + nt * 16 + g) * 64 + kk * 32 + q * 8];
#pragma unroll
        for (int j = 0; j < 8; j++) v[j] = (__bf16)((float)v[j] * cs);
        bq[nt][kk] = v;
      }
  }

  short8_t kreg[4], vreg[4];
  auto loadKV = [&](int kt) {
    const short* Kp  = Kg + base + (size_t)kt * 128 * 64;
    const short* Vtp = Vt + base + (size_t)kt * 128;
#pragma unroll
    for (int i = 0; i < 4; i++) {
      int c = tid + i * 256;
      kreg[i] = *(const short8_t*)&Kp[(c >> 3) * 64 + (c & 7) * 8];
      vreg[i] = *(const short8_t*)&Vtp[(size_t)(c >> 4) * 2048 + (c & 15) * 8];
    }
  };
  auto storeKV = [&]() {
#pragma unroll
    for (int i = 0; i < 4; i++) {
      int c = tid + i * 256;
      *(short8_t*)&Ks[(c >> 3) * 72 + (c & 7) * 8] = kreg[i];
      *(short8_t*)&VTs[(c >> 4) * 136 + (c & 15) * 8] = vreg[i];
    }
  };

  f32x4 ot[4][2] = {};
  float m_run[2] = {-1e30f, -1e30f};
  float l_run[2] = {0.0f, 0.0f};

  auto compute = [&](auto diagc) {
    constexpr bool DIAG = decltype(diagc)::value;
    // S^T = K * Q^T
    f32x4 st[8][2] = {};
#pragma unroll
    for (int kk = 0; kk < 2; kk++)
#pragma unroll
      for (int mt = 0; mt < 8; mt++) {
        bf16x8 ak = *(const bf16x8*)&Ks[(mt * 16 + g) * 72 + kk * 32 + q * 8];
#pragma unroll
        for (int nt = 0; nt < 2; nt++)
          st[mt][nt] = __builtin_amdgcn_mfma_f32_16x16x32_bf16(ak, bq[nt][kk],
                                                               st[mt][nt], 0, 0, 0);
      }

    short4_t pk[8][2];
#pragma unroll
    for (int nt = 0; nt < 2; nt++) {
      const int qloc = wave * 32 + nt * 16 + g;
      float tmax = -1e30f;
#pragma unroll
      for (int mt = 0; mt < 8; mt++)
#pragma unroll
        for (int r = 0; r < 4; r++) {
          if (DIAG) {
            if (mt * 16 + q * 4 + r > qloc) st[mt][nt][r] = -1e30f;
          }
          tmax = fmaxf(tmax, st[mt][nt][r]);
        }
      tmax = fmaxf(tmax, __shfl_xor(tmax, 16));
      tmax = fmaxf(tmax, __shfl_xor(tmax, 32));
      const float mnew = fmaxf(m_run[nt], tmax);
      const float alpha = __builtin_amdgcn_exp2f(m_run[nt] - mnew);
      float psum = 0.0f;
#pragma unroll
      for (int mt = 0; mt < 8; mt++)
#pragma unroll
        for (int r = 0; r < 4; r++) {
          float p = __builtin_amdgcn_exp2f(st[mt][nt][r] - mnew);
          psum += p;
          pk[mt][nt][r] = f2bf(p);
        }
      psum += __shfl_xor(psum, 16);
      psum += __shfl_xor(psum, 32);
      l_run[nt] = l_run[nt] * alpha + psum;
      m_run[nt] = mnew;
#pragma unroll
      for (int mt = 0; mt < 4; mt++) {
        ot[mt][nt][0] *= alpha; ot[mt][nt][1] *= alpha;
        ot[mt][nt][2] *= alpha; ot[mt][nt][3] *= alpha;
      }
    }

    // O^T += V^T * P^T in two key-halves through the half-width P buffer.
    short* Pw = &Ps[wave][0];
#pragma unroll
    for (int half = 0; half < 2; half++) {
#pragma unroll
      for (int nt = 0; nt < 2; nt++)
#pragma unroll
        for (int mh = 0; mh < 4; mh++)
          *(short4_t*)&Pw[(nt * 16 + g) * 72 + mh * 16 + q * 4] =
              pk[half * 4 + mh][nt];
#pragma unroll
      for (int kh = 0; kh < 2; kh++) {
        const int kk = half * 2 + kh;
        bf16x8 pb[2];
#pragma unroll
        for (int nt = 0; nt < 2; nt++)
          pb[nt] = *(const bf16x8*)&Pw[(nt * 16 + g) * 72 + kh * 32 + q * 8];
#pragma unroll
        for (int mt = 0; mt < 4; mt++) {
          bf16x8 av = *(const bf16x8*)&VTs[(mt * 16 + g) * 136 + kk * 32 + q * 8];
#pragma unroll
          for (int nt = 0; nt < 2; nt++)
            ot[mt][nt] = __builtin_amdgcn_mfma_f32_16x16x32_bf16(av, pb[nt],
                                                                 ot[mt][nt], 0, 0, 0);
        }
      }
    }
  };

  loadKV(0);
  for (int kt = 0; kt < qt; kt++) {
    __syncthreads();
    storeKV();
    loadKV(kt + 1);                      // prefetch flies across compute
    __syncthreads();
    compute(std::integral_constant<bool, false>{});
  }
  __syncthreads();
  storeKV();
  __syncthreads();
  compute(std::integral_constant<bool, true>{});

  // epilogue: O[b, qrow, h*64+d] = O^T / l
#pragma unroll
  for (int nt = 0; nt < 2; nt++) {
    const float inv = 1.0f / l_run[nt];
    const int qrow = qt * 128 + wave * 32 + nt * 16 + g;
    size_t obase = ((size_t)b * 2048 + qrow) * 1024 + h * 64;
#pragma unroll
    for (int mt = 0; mt < 4; mt++) {
      short4_t ov;
#pragma unroll
      for (int r = 0; r < 4; r++) ov[r] = f2bf(ot[mt][nt][r] * inv);
      *(short4_t*)&Og[obase + mt * 16 + q * 4] = ov;
    }
  }
}

// ---------------- launch ----------------
extern "C" void kernel_launch(void* const* d_in, const int* in_sizes, int n_in,
                              void* d_out, int out_size, void* d_ws, size_t ws_size,
                              hipStream_t stream) {
  const float* x      = (const float*)d_in[0];   // [4,2048,1024]
  const float* w_qkv  = (const float*)d_in[1];   // [1024,3072]
  const float* w_proj = (const float*)d_in[2];   // [1024,1024]
  float* out = (float*)d_out;                    // [4,2048,1024]

  char* ws = (char*)d_ws;
  short* wqkvT  = (short*)(ws);                    // 6 MB  [3072][1024]
  short* wprojT = (short*)(ws + 6291456);          // 2 MB  [1024][1024]
  short* Qb     = (short*)(ws + 8388608);          // 16 MB [B,H,T,D]
  short* Kb     = (short*)(ws + 25165824);         // 16 MB [B,H,T,D]
  short* Vtb    = (short*)(ws + 41943040);         // 16 MB [B,H,D,T]
  short* Ob     = (short*)(ws + 58720256);         // 16 MB [B,T,C]  (end 72 MiB)

  {
    dim3 gq(96, 32); transpose_bf16<<<gq, 256, 0, stream>>>(w_qkv, wqkvT, 1024, 3072);
    dim3 gp(32, 32); transpose_bf16<<<gp, 256, 0, stream>>>(w_proj, wprojT, 1024, 1024);
  }
  {
    dim3 g(24, 64);  // N/128, M/128 ; gridDim.x%8==0 pins B-columns to XCDs
    gemm_bt<1, true><<<g, 256, 0, stream>>>(x, wqkvT, nullptr, Qb, Kb, Vtb,
                                            8192, 3072, 1024);
  }
  {
    attn_fwd<<<dim3(1024), 256, 0, stream>>>(Qb, Kb, Vtb, Ob);
  }
  {
    dim3 g(8, 64);
    gemm_bt<0, false><<<g, 256, 0, stream>>>(Ob, wprojT, out, nullptr, nullptr,
                                             nullptr, 8192, 1024, 1024);
  }
}

// Round 4
// 264.459 us; speedup vs baseline: 1.2112x; 1.2112x over previous
//
#include <hip/hip_runtime.h>
#include <cstdint>
#include <cstddef>
#include <type_traits>

typedef float  f32x4    __attribute__((ext_vector_type(4)));
typedef __bf16 bf16x8   __attribute__((ext_vector_type(8)));
typedef short  short4_t __attribute__((ext_vector_type(4)));
typedef short  short8_t __attribute__((ext_vector_type(8)));

__device__ __forceinline__ short f2bf(float f) {
  return __builtin_bit_cast(short, (__bf16)f);   // hw cvt, RNE
}

// ---------------- transpose-convert W[K][N] fp32 -> WT[N][K] bf16 ----------------
__global__ void transpose_bf16(const float* __restrict__ W, short* __restrict__ WT,
                               int K, int N) {
  __shared__ float tile[32][33];
  int tx = threadIdx.x & 31, ty = threadIdx.x >> 5;
  int n0 = blockIdx.x * 32, k0 = blockIdx.y * 32;
#pragma unroll
  for (int i = 0; i < 32; i += 8)
    tile[ty + i][tx] = W[(size_t)(k0 + ty + i) * N + n0 + tx];
  __syncthreads();
#pragma unroll
  for (int i = 0; i < 32; i += 8)
    WT[(size_t)(n0 + ty + i) * K + k0 + tx] = f2bf(tile[tx][ty + i]);
}

// ---------------- pipelined bf16 GEMM, Bt is [N][K] bf16 ----------------
// A: fp32 (AF32) or bf16. Register-prefetch staging: global->VGPR issued a full
// compute phase before the VGPR->LDS write, so the barrier drains only lgkmcnt.
// launch_bounds(256,2): 256-reg total cap — staging regs + 64 acc fit, NO spill
// (R3's (256,4) cap of 128 caused scratch spills).
// MODE 0: fp32 out [M][N].  MODE 1: Q/K [B,H,T,D] via LDS-coalesced stores,
// V^T [B,H,D,T] via packed direct stores.
template <int MODE, bool AF32>
__global__ __launch_bounds__(256, 2) void gemm_bt(
    const void* __restrict__ Av, const short* __restrict__ Bt,
    float* __restrict__ outf, short* __restrict__ Qo, short* __restrict__ Ko,
    short* __restrict__ Vo, int M, int N, int K) {
  constexpr int SMEM = (MODE == 1) ? (128 * 136 * 2) : 16384;
  __shared__ alignas(16) char smem[SMEM];
  short* As = (short*)smem;             // [128][32]
  short* Bs = (short*)(smem + 8192);    // [128][32]

  const int tid = threadIdx.x;
  const int lane = tid & 63, wave = tid >> 6;
  const int g = lane & 15, q = lane >> 4;
  const int m0 = blockIdx.y * 128, n0 = blockIdx.x * 128;
  const int wm = (wave >> 1) * 64, wn = (wave & 1) * 64;

  const int srow = tid >> 2;            // 0..63
  const int scol = (tid & 3) * 8;
  const float* Af = (const float*)Av;
  const short* Ab = (const short*)Av;

  f32x4    raf[4];
  short8_t ra[2], rb[2];

  auto load_regs = [&](int k0) {
    if constexpr (AF32) {
      const float* p0 = &Af[(size_t)(m0 + srow) * K + k0 + scol];
      const float* p1 = &Af[(size_t)(m0 + 64 + srow) * K + k0 + scol];
      raf[0] = *(const f32x4*)p0; raf[1] = *(const f32x4*)(p0 + 4);
      raf[2] = *(const f32x4*)p1; raf[3] = *(const f32x4*)(p1 + 4);
    } else {
      ra[0] = *(const short8_t*)&Ab[(size_t)(m0 + srow) * K + k0 + scol];
      ra[1] = *(const short8_t*)&Ab[(size_t)(m0 + 64 + srow) * K + k0 + scol];
    }
    rb[0] = *(const short8_t*)&Bt[(size_t)(n0 + srow) * K + k0 + scol];
    rb[1] = *(const short8_t*)&Bt[(size_t)(n0 + 64 + srow) * K + k0 + scol];
  };
  auto store_regs = [&]() {
    short8_t w0, w1;
    if constexpr (AF32) {
#pragma unroll
      for (int j = 0; j < 4; j++) {
        w0[j] = f2bf(raf[0][j]); w0[4 + j] = f2bf(raf[1][j]);
        w1[j] = f2bf(raf[2][j]); w1[4 + j] = f2bf(raf[3][j]);
      }
    } else { w0 = ra[0]; w1 = ra[1]; }
    *(short8_t*)&As[tid * 8] = w0;
    *(short8_t*)&As[(tid + 256) * 8] = w1;
    *(short8_t*)&Bs[tid * 8] = rb[0];
    *(short8_t*)&Bs[(tid + 256) * 8] = rb[1];
  };

  f32x4 acc[4][4] = {};
  const int KB = K >> 5;
  load_regs(0);
  for (int kb = 0; kb < KB; kb++) {
    __syncthreads();                 // prior tile's consumers done
    store_regs();                    // waits vmcnt (issued a phase ago)
    if (kb + 1 < KB) load_regs((kb + 1) << 5);  // fly during compute
    __syncthreads();
    bf16x8 af[4], bfr[4];
#pragma unroll
    for (int mt = 0; mt < 4; mt++)
      af[mt] = *(const bf16x8*)&As[(wm + mt * 16 + g) * 32 + q * 8];
#pragma unroll
    for (int nt = 0; nt < 4; nt++)
      bfr[nt] = *(const bf16x8*)&Bs[(wn + nt * 16 + g) * 32 + q * 8];
#pragma unroll
    for (int mt = 0; mt < 4; mt++)
#pragma unroll
      for (int nt = 0; nt < 4; nt++)
        acc[mt][nt] = __builtin_amdgcn_mfma_f32_16x16x32_bf16(af[mt], bfr[nt],
                                                              acc[mt][nt], 0, 0, 0);
  }

  if (MODE == 0) {
#pragma unroll
    for (int mt = 0; mt < 4; mt++)
#pragma unroll
      for (int nt = 0; nt < 4; nt++) {
        int n = n0 + wn + nt * 16 + g;
        int mbase = m0 + wm + mt * 16 + q * 4;
#pragma unroll
        for (int r = 0; r < 4; r++)
          outf[(size_t)(mbase + r) * N + n] = acc[mt][nt][r];
      }
  } else {
    const int which = n0 >> 10;          // uniform per block
    const int b = m0 >> 11;              // uniform per block
    if (which == 2) {
      // V^T [b,h,d,t]: t consecutive over r -> packed 8B stores
#pragma unroll
      for (int nt = 0; nt < 4; nt++) {
        int c = (n0 + wn + nt * 16 + g) & 1023;
        int h = c >> 6, d = c & 63;
#pragma unroll
        for (int mt = 0; mt < 4; mt++) {
          int t = (m0 + wm + mt * 16 + q * 4) & 2047;
          short4_t pv;
#pragma unroll
          for (int r = 0; r < 4; r++) pv[r] = f2bf(acc[mt][nt][r]);
          *(short4_t*)&Vo[((size_t)((b << 4) + h) * 64 + d) * 2048 + t] = pv;
        }
      }
    } else {
      // Q/K: stage C-tile in LDS, store coalesced 16B
      __syncthreads();
      short* Cs = (short*)smem;          // [128][136]
#pragma unroll
      for (int mt = 0; mt < 4; mt++)
#pragma unroll
        for (int nt = 0; nt < 4; nt++)
#pragma unroll
          for (int r = 0; r < 4; r++)
            Cs[(wm + mt * 16 + q * 4 + r) * 136 + wn + nt * 16 + g] =
                f2bf(acc[mt][nt][r]);
      __syncthreads();
      short* dst = (which == 0) ? Qo : Ko;
      const int h0 = (n0 & 1023) >> 6;
      const int trow = tid >> 1, half = tid & 1;
      const int t = (m0 + trow) & 2047;
      const size_t gb = ((size_t)((b << 4) + h0 + half) * 2048 + t) * 64;
#pragma unroll
      for (int j = 0; j < 8; j++)
        *(short8_t*)&dst[gb + j * 8] =
            *(const short8_t*)&Cs[trow * 136 + half * 64 + j * 8];
    }
  }
}

// ---------------- causal flash attention ----------------
// Q,K: [B,H,T,D] bf16.  Vt: [B,H,D,T] bf16.  O: [B,T,H*D] bf16.
// One q-tile per block; 1024 blocks, qt descending (heavy first), bh in low
// 6 bits so each (b,h)'s K/V pins to one XCD L2 (id%8==bh%8).
// Split softmax: exp+P-store in two key-halves through a half-width per-wave
// P buffer (NO pk register array — R3's spilled). launch_bounds(256,2);
// LDS 54272 B -> 3 blocks/CU if total regs land <=170, else 2.
__global__ __launch_bounds__(256, 2) void attn_fwd(
    const short* __restrict__ Qg, const short* __restrict__ Kg,
    const short* __restrict__ Vt, short* __restrict__ Og) {
  __shared__ alignas(16) short Ks[128 * 72];     // [key][64+8]
  __shared__ alignas(16) short VTs[64 * 136];    // [d][128+8]
  __shared__ alignas(16) short Ps[4][32 * 72];   // per-wave P [32 qrows][64+8]

  const int tid = threadIdx.x, lane = tid & 63, wave = tid >> 6;
  const int g = lane & 15, q = lane >> 4;
  const int id = blockIdx.x;
  const int bh = id & 63;
  const int qt = 15 - (id >> 6);
  const size_t base = (size_t)bh * (2048 * 64);
  const int b = bh >> 4, h = bh & 15;
  const float cs = 0.18033688011f;     // (1/sqrt(64)) * log2(e)

  // Q fragments: direct global loads, pre-scaled
  bf16x8 bq[2][2];
  {
    const short* Qp = Qg + base + (size_t)qt * 128 * 64;
#pragma unroll
    for (int nt = 0; nt < 2; nt++)
#pragma unroll
      for (int kk = 0; kk < 2; kk++) {
        bf16x8 v = *(const bf16x8*)&Qp[(wave * 32 + nt * 16 + g) * 64 + kk * 32 + q * 8];
#pragma unroll
        for (int j = 0; j < 8; j++) v[j] = (__bf16)((float)v[j] * cs);
        bq[nt][kk] = v;
      }
  }

  short8_t kreg[4], vreg[4];
  auto loadKV = [&](int kt) {
    const short* Kp  = Kg + base + (size_t)kt * 128 * 64;
    const short* Vtp = Vt + base + (size_t)kt * 128;
#pragma unroll
    for (int i = 0; i < 4; i++) {
      int c = tid + i * 256;
      kreg[i] = *(const short8_t*)&Kp[(c >> 3) * 64 + (c & 7) * 8];
      vreg[i] = *(const short8_t*)&Vtp[(size_t)(c >> 4) * 2048 + (c & 15) * 8];
    }
  };
  auto storeKV = [&]() {
#pragma unroll
    for (int i = 0; i < 4; i++) {
      int c = tid + i * 256;
      *(short8_t*)&Ks[(c >> 3) * 72 + (c & 7) * 8] = kreg[i];
      *(short8_t*)&VTs[(c >> 4) * 136 + (c & 15) * 8] = vreg[i];
    }
  };

  f32x4 ot[4][2] = {};
  float m_run[2] = {-1e30f, -1e30f};
  float l_run[2] = {0.0f, 0.0f};

  auto compute = [&](auto diagc) {
    constexpr bool DIAG = decltype(diagc)::value;
    // S^T = K * Q^T
    f32x4 st[8][2] = {};
#pragma unroll
    for (int kk = 0; kk < 2; kk++)
#pragma unroll
      for (int mt = 0; mt < 8; mt++) {
        bf16x8 ak = *(const bf16x8*)&Ks[(mt * 16 + g) * 72 + kk * 32 + q * 8];
#pragma unroll
        for (int nt = 0; nt < 2; nt++)
          st[mt][nt] = __builtin_amdgcn_mfma_f32_16x16x32_bf16(ak, bq[nt][kk],
                                                               st[mt][nt], 0, 0, 0);
      }

    // row max (+ diag mask), rescale O
    float mnew[2], alpha[2], psum[2];
#pragma unroll
    for (int nt = 0; nt < 2; nt++) {
      const int qloc = wave * 32 + nt * 16 + g;
      float tmax = -1e30f;
#pragma unroll
      for (int mt = 0; mt < 8; mt++)
#pragma unroll
        for (int r = 0; r < 4; r++) {
          if (DIAG) {
            if (mt * 16 + q * 4 + r > qloc) st[mt][nt][r] = -1e30f;
          }
          tmax = fmaxf(tmax, st[mt][nt][r]);
        }
      tmax = fmaxf(tmax, __shfl_xor(tmax, 16));
      tmax = fmaxf(tmax, __shfl_xor(tmax, 32));
      mnew[nt] = fmaxf(m_run[nt], tmax);
      alpha[nt] = __builtin_amdgcn_exp2f(m_run[nt] - mnew[nt]);
      m_run[nt] = mnew[nt];
      psum[nt] = 0.0f;
#pragma unroll
      for (int mt = 0; mt < 4; mt++) {
        ot[mt][nt][0] *= alpha[nt]; ot[mt][nt][1] *= alpha[nt];
        ot[mt][nt][2] *= alpha[nt]; ot[mt][nt][3] *= alpha[nt];
      }
    }

    // exp + P-store + PV, in two key-halves (P written straight to LDS;
    // same-wave in-order DS ops make the buffer reuse safe)
    short* Pw = &Ps[wave][0];
#pragma unroll
    for (int half = 0; half < 2; half++) {
#pragma unroll
      for (int nt = 0; nt < 2; nt++)
#pragma unroll
        for (int mh = 0; mh < 4; mh++) {
          const int mt = half * 4 + mh;
          short4_t pk4;
#pragma unroll
          for (int r = 0; r < 4; r++) {
            float p = __builtin_amdgcn_exp2f(st[mt][nt][r] - mnew[nt]);
            psum[nt] += p;
            pk4[r] = f2bf(p);
          }
          *(short4_t*)&Pw[(nt * 16 + g) * 72 + mh * 16 + q * 4] = pk4;
        }
#pragma unroll
      for (int kh = 0; kh < 2; kh++) {
        const int kk = half * 2 + kh;
        bf16x8 pb[2];
#pragma unroll
        for (int nt = 0; nt < 2; nt++)
          pb[nt] = *(const bf16x8*)&Pw[(nt * 16 + g) * 72 + kh * 32 + q * 8];
#pragma unroll
        for (int mt = 0; mt < 4; mt++) {
          bf16x8 av = *(const bf16x8*)&VTs[(mt * 16 + g) * 136 + kk * 32 + q * 8];
#pragma unroll
          for (int nt = 0; nt < 2; nt++)
            ot[mt][nt] = __builtin_amdgcn_mfma_f32_16x16x32_bf16(av, pb[nt],
                                                                 ot[mt][nt], 0, 0, 0);
        }
      }
    }

#pragma unroll
    for (int nt = 0; nt < 2; nt++) {
      float ps = psum[nt];
      ps += __shfl_xor(ps, 16);
      ps += __shfl_xor(ps, 32);
      l_run[nt] = l_run[nt] * alpha[nt] + ps;
    }
  };

  loadKV(0);
  for (int kt = 0; kt < qt; kt++) {
    __syncthreads();
    storeKV();
    loadKV(kt + 1);                      // prefetch flies across compute
    __syncthreads();
    compute(std::integral_constant<bool, false>{});
  }
  __syncthreads();
  storeKV();
  __syncthreads();
  compute(std::integral_constant<bool, true>{});

  // epilogue: O[b, qrow, h*64+d] = O^T / l
#pragma unroll
  for (int nt = 0; nt < 2; nt++) {
    const float inv = 1.0f / l_run[nt];
    const int qrow = qt * 128 + wave * 32 + nt * 16 + g;
    size_t obase = ((size_t)b * 2048 + qrow) * 1024 + h * 64;
#pragma unroll
    for (int mt = 0; mt < 4; mt++) {
      short4_t ov;
#pragma unroll
      for (int r = 0; r < 4; r++) ov[r] = f2bf(ot[mt][nt][r] * inv);
      *(short4_t*)&Og[obase + mt * 16 + q * 4] = ov;
    }
  }
}

// ---------------- launch ----------------
extern "C" void kernel_launch(void* const* d_in, const int* in_sizes, int n_in,
                              void* d_out, int out_size, void* d_ws, size_t ws_size,
                              hipStream_t stream) {
  const float* x      = (const float*)d_in[0];   // [4,2048,1024]
  const float* w_qkv  = (const float*)d_in[1];   // [1024,3072]
  const float* w_proj = (const float*)d_in[2];   // [1024,1024]
  float* out = (float*)d_out;                    // [4,2048,1024]

  char* ws = (char*)d_ws;
  short* wqkvT  = (short*)(ws);                    // 6 MB  [3072][1024]
  short* wprojT = (short*)(ws + 6291456);          // 2 MB  [1024][1024]
  short* Qb     = (short*)(ws + 8388608);          // 16 MB [B,H,T,D]
  short* Kb     = (short*)(ws + 25165824);         // 16 MB [B,H,T,D]
  short* Vtb    = (short*)(ws + 41943040);         // 16 MB [B,H,D,T]
  short* Ob     = (short*)(ws + 58720256);         // 16 MB [B,T,C]  (end 72 MiB)

  {
    dim3 gq(96, 32); transpose_bf16<<<gq, 256, 0, stream>>>(w_qkv, wqkvT, 1024, 3072);
    dim3 gp(32, 32); transpose_bf16<<<gp, 256, 0, stream>>>(w_proj, wprojT, 1024, 1024);
  }
  {
    dim3 g(24, 64);  // N/128, M/128
    gemm_bt<1, true><<<g, 256, 0, stream>>>(x, wqkvT, nullptr, Qb, Kb, Vtb,
                                            8192, 3072, 1024);
  }
  {
    attn_fwd<<<dim3(1024), 256, 0, stream>>>(Qb, Kb, Vtb, Ob);
  }
  {
    dim3 g(8, 64);
    gemm_bt<0, false><<<g, 256, 0, stream>>>(Ob, wprojT, out, nullptr, nullptr,
                                             nullptr, 8192, 1024, 1024);
  }
}